// Round 4
// baseline (371.125 us; speedup 1.0000x reference)
//
#include <hip/hip_runtime.h>

// Problem constants
#define BB 4
#define SS 4096
#define DIN 1024      // K for both GEMMs
#define DH 1024       // combined fast+slow channels
#define PN 2048       // GEMM1 logical output cols (z -> Zarr, h~ -> Harr)
#define MM (BB*SS)    // 16384 rows
#define NC 64         // scan chunks
#define CL 64         // chunk length (NC*CL == SS)

typedef unsigned short ushort_t;
typedef __attribute__((ext_vector_type(8))) short bf16x8;
typedef __attribute__((ext_vector_type(4))) float f32x4;
typedef __attribute__((ext_vector_type(4))) unsigned short u16x4;

__device__ inline float bf2f(ushort_t u) {
    union { float f; unsigned int i; } v; v.i = ((unsigned int)u) << 16; return v.f;
}
__device__ inline ushort_t f2bf(float f) {
    union { float f; unsigned int i; } v; v.f = f;
    unsigned int r = v.i + 0x7fffu + ((v.i >> 16) & 1u);  // round-to-nearest-even
    return (ushort_t)(r >> 16);
}
__device__ inline float sigmoidf_(float x) { return 1.0f / (1.0f + __expf(-x)); }

__device__ inline void load_lds16(const void* g, void* l) {
    __builtin_amdgcn_global_load_lds(
        (const __attribute__((address_space(1))) void*)g,
        (__attribute__((address_space(3))) void*)l, 16, 0, 0);
}

// ---------------------------------------------------------------------------
// Fallback (ws too small telemetry): write fp32 zeros to out.
__global__ void zero_out_kernel(float* out, int n) {
    int i = blockIdx.x * 256 + threadIdx.x;
    if (i < n) out[i] = 0.0f;
}

// ---------------------------------------------------------------------------
// Elementwise fp32 -> bf16 convert (n multiple of 4).
__global__ __launch_bounds__(256) void cvt_f32_bf16(
    const float* __restrict__ src, ushort_t* __restrict__ dst, int n)
{
    int i = (blockIdx.x * 256 + threadIdx.x) * 4;
    if (i >= n) return;
    float4 v = *(const float4*)(src + i);
    u16x4 o;
    o.x = f2bf(v.x); o.y = f2bf(v.y); o.z = f2bf(v.z); o.w = f2bf(v.w);
    *(u16x4*)(dst + i) = o;
}

// ---------------------------------------------------------------------------
// Transpose + convert: dst[n][k] = bf16(src[k][n]).  src: K x srcN fp32 rm.
// grid: (K/64, srcN/64), block 256.
__global__ __launch_bounds__(256) void transpose_cvt(
    const float* __restrict__ src, int srcN,
    ushort_t* __restrict__ dst, int K)
{
    __shared__ ushort_t tile[64][65];
    const int k0 = blockIdx.x * 64, n0 = blockIdx.y * 64;
    const int tx = threadIdx.x & 63, ty = threadIdx.x >> 6;  // ty in [0,4)
    #pragma unroll
    for (int i = ty; i < 64; i += 4)
        tile[i][tx] = f2bf(src[(size_t)(k0 + i) * srcN + n0 + tx]);
    __syncthreads();
    #pragma unroll
    for (int i = ty; i < 64; i += 4)
        dst[(size_t)(n0 + i) * K + k0 + tx] = tile[tx][i];
}

// ---------------------------------------------------------------------------
// Concatenate the four fp32 z/h biases into bcat[2048].
__global__ void bias_concat(const float* __restrict__ bzf, const float* __restrict__ bzs,
                            const float* __restrict__ bhf, const float* __restrict__ bhs,
                            float* __restrict__ bcat)
{
    int i = blockIdx.x * 256 + threadIdx.x;  // 0..2047
    float v = (i < 512) ? bzf[i] : (i < 1024) ? bzs[i - 512]
            : (i < 1536) ? bhf[i - 1024] : bhs[i - 1536];
    bcat[i] = v;
}

// ---------------------------------------------------------------------------
// GEMM: C(M x N) = A(M x K, bf16 rm, row stride lda) * Bt(N x K, bf16 rm)^T
// 128x128 tile, BK=64, 256 threads (4 waves 2x2, each 64x64 via 4x4 mfma 16x16x32).
// EPI=0 (N=2048): col<1024  -> Zarr[row*DH+col]     = bf16(sigmoid(acc+bias[col]))
//                 col>=1024 -> Harr[row*DH+col-1024] = bf16(acc+bias[col])
// EPI=1 (N=1024): Out[row*DH+col] = sigmoid(acc + bg[col]) * bf2f(Hbf[row*DH+col])  (fp32)
template <int EPI>
__global__ __launch_bounds__(256) void gemm_kernel(
    const ushort_t* __restrict__ A, const ushort_t* __restrict__ Bt,
    int K, int lda,
    const float* __restrict__ bias,
    ushort_t* __restrict__ Zarr, ushort_t* __restrict__ Harr,
    const float* __restrict__ bg, const ushort_t* __restrict__ Hbf,
    float* __restrict__ Out)
{
    __shared__ alignas(16) ushort_t As[128 * 64];
    __shared__ alignas(16) ushort_t Bs[128 * 64];

    const int tid  = threadIdx.x;
    const int lane = tid & 63;
    const int wave = tid >> 6;
    const int wm   = wave & 1;       // wave row (2x2 grid of waves)
    const int wn   = wave >> 1;      // wave col
    const int lrow = lane & 15;      // m (A) / n (B) / col (C)
    const int kgrp = lane >> 4;      // k-group: k = kgrp*8 + j

    const int mBase = blockIdx.x * 128;
    const int nBase = blockIdx.y * 128;

    f32x4 acc[4][4] = {};

    const ushort_t* Ablk = A  + (size_t)mBase * lda;
    const ushort_t* Bblk = Bt + (size_t)nBase * K;

    for (int k0 = 0; k0 < K; k0 += 64) {
        #pragma unroll
        for (int i = 0; i < 4; i++) {
            int idx = i * 256 + tid;          // 0..1023 chunks of 16B
            int r   = idx >> 3;               // row 0..127
            int c   = (idx & 7) * 8;          // col 0,8,...,56
            load_lds16(Ablk + (size_t)r * lda + k0 + c, &As[idx * 8]);
            load_lds16(Bblk + (size_t)r * K   + k0 + c, &Bs[idx * 8]);
        }
        __syncthreads();                      // drains vmcnt for global_load_lds

        #pragma unroll
        for (int kk = 0; kk < 64; kk += 32) {
            bf16x8 af[4], bfr[4];
            #pragma unroll
            for (int mt = 0; mt < 4; mt++)
                af[mt] = *(const bf16x8*)&As[(wm * 64 + mt * 16 + lrow) * 64 + kk + kgrp * 8];
            #pragma unroll
            for (int nt = 0; nt < 4; nt++)
                bfr[nt] = *(const bf16x8*)&Bs[(wn * 64 + nt * 16 + lrow) * 64 + kk + kgrp * 8];
            #pragma unroll
            for (int mt = 0; mt < 4; mt++)
                #pragma unroll
                for (int nt = 0; nt < 4; nt++)
                    acc[mt][nt] = __builtin_amdgcn_mfma_f32_16x16x32_bf16(
                        af[mt], bfr[nt], acc[mt][nt], 0, 0, 0);
        }
        __syncthreads();
    }

    // Epilogue. C/D layout: col = lane&15, row = (lane>>4)*4 + reg  [m89/m91]
    const int row0  = mBase + wm * 64;
    const int col0  = nBase + wn * 64;
    const int rquad = (lane >> 4) * 4;

    if (EPI == 0) {
        const bool isz = (nBase < DH);   // whole 128-col block is z-cols or h~-cols
        ushort_t* Dst  = isz ? Zarr : Harr;
        const int csub = isz ? 0 : DH;
        #pragma unroll
        for (int nt = 0; nt < 4; nt++) {
            int col  = col0 + nt * 16 + lrow;
            float bv = bias[col];
            int dcol = col - csub;
            #pragma unroll
            for (int mt = 0; mt < 4; mt++) {
                int row = row0 + mt * 16 + rquad;
                ushort_t* p = Dst + (size_t)row * DH + dcol;
                #pragma unroll
                for (int r = 0; r < 4; r++) {
                    float v = acc[mt][nt][r] + bv;
                    if (isz) v = sigmoidf_(v);
                    p[(size_t)r * DH] = f2bf(v);
                }
            }
        }
    } else {
        #pragma unroll
        for (int nt = 0; nt < 4; nt++) {
            int col  = col0 + nt * 16 + lrow;
            float bv = bg[col];
            #pragma unroll
            for (int mt = 0; mt < 4; mt++) {
                int row = row0 + mt * 16 + rquad;
                #pragma unroll
                for (int r = 0; r < 4; r++) {
                    float g = sigmoidf_(acc[mt][nt][r] + bv);
                    float h = bf2f(Hbf[(size_t)(row + r) * DH + col]);
                    Out[(size_t)(row + r) * DH + col] = g * h;
                }
            }
        }
    }
}

// ---------------------------------------------------------------------------
// Scan pass 1: per-chunk aggregates. h_t = a*h + b with a = 1-z, b = z*h_tilde.
__global__ __launch_bounds__(256) void scan_chunk_agg(
    const ushort_t* __restrict__ Zarr, const ushort_t* __restrict__ Harr,
    float* __restrict__ Agg, float* __restrict__ Bagg)
{
    const int c     = blockIdx.x * 256 + threadIdx.x;   // channel 0..1023
    const int chunk = blockIdx.y;
    const int b     = blockIdx.z;
    const size_t s0 = (size_t)(b * SS + chunk * CL);
    const ushort_t* Zp = Zarr + s0 * DH + c;
    const ushort_t* Hp = Harr + s0 * DH + c;
    float A = 1.0f, Bg = 0.0f;
    #pragma unroll 4
    for (int t = 0; t < CL; t++) {
        float z  = bf2f(Zp[(size_t)t * DH]);
        float ht = bf2f(Hp[(size_t)t * DH]);
        float a  = 1.0f - z;
        A  = A * a;
        Bg = a * Bg + z * ht;
    }
    const int idx = (b * NC + chunk) * DH + c;
    Agg[idx]  = A;
    Bagg[idx] = Bg;
}

// Scan pass 2: carry across chunks. 4096 threads, 64 sequential steps.
__global__ void scan_carry(const float* __restrict__ Agg, const float* __restrict__ Bagg,
                           float* __restrict__ Hinit)
{
    const int i = blockIdx.x * 256 + threadIdx.x;  // 0..4095
    const int b = i >> 10, c = i & 1023;
    float h = 0.0f;
    for (int j = 0; j < NC; j++) {
        const int idx = (b * NC + j) * DH + c;
        Hinit[idx] = h;
        h = Agg[idx] * h + Bagg[idx];
    }
}

// Scan pass 3: re-apply with chunk-initial h; write h (bf16) in place over Harr.
__global__ __launch_bounds__(256) void scan_apply(
    const ushort_t* __restrict__ Zarr, ushort_t* Harr, const float* __restrict__ Hinit)
{
    const int c     = blockIdx.x * 256 + threadIdx.x;
    const int chunk = blockIdx.y;
    const int b     = blockIdx.z;
    const size_t s0 = (size_t)(b * SS + chunk * CL);
    const ushort_t* Zp = Zarr + s0 * DH + c;
    ushort_t* Hp = Harr + s0 * DH + c;
    float h = Hinit[(b * NC + chunk) * DH + c];
    #pragma unroll 4
    for (int t = 0; t < CL; t++) {
        float z  = bf2f(Zp[(size_t)t * DH]);
        float ht = bf2f(Hp[(size_t)t * DH]);
        h = (1.0f - z) * h + z * ht;
        Hp[(size_t)t * DH] = f2bf(h);
    }
}

// ---------------------------------------------------------------------------
extern "C" void kernel_launch(void* const* d_in, const int* in_sizes, int n_in,
                              void* d_out, int out_size, void* d_ws, size_t ws_size,
                              hipStream_t stream)
{
    // All inputs fp32 per the reference; output fp32 (16M elements = 64 MiB).
    const float* x   = (const float*)d_in[0];
    const float* Wzf = (const float*)d_in[1];
    const float* bzf = (const float*)d_in[2];
    const float* Whf = (const float*)d_in[3];
    const float* bhf = (const float*)d_in[4];
    const float* Wzs = (const float*)d_in[5];
    const float* bzs = (const float*)d_in[6];
    const float* Whs = (const float*)d_in[7];
    const float* bhs = (const float*)d_in[8];
    const float* Wg  = (const float*)d_in[9];
    const float* bg  = (const float*)d_in[10];

    const size_t NEED = (size_t)42 << 20;   // 42 MiB (known to fit from round 3)
    if (ws_size < NEED) {
        zero_out_kernel<<<(MM * DH + 255) / 256, 256, 0, stream>>>((float*)d_out, MM * DH);
        return;
    }

    // Workspace layout (42 MiB):
    char* ws = (char*)d_ws;
    ushort_t* WcatT = (ushort_t*)(ws);                                    // 0..4 MiB: 2048x1024 bf16
    ushort_t* WgT   = (ushort_t*)(ws + ((size_t)4 << 20));                // 4..6 MiB: 1024x1024 bf16
    float*    bcat  = (float*)   (ws + ((size_t)6 << 20));                // 8 KiB
    float*    Agg   = (float*)   (ws + ((size_t)6 << 20) + (64 << 10));   // 1 MiB
    float*    Bagg  = (float*)   (ws + ((size_t)7 << 20) + (64 << 10));   // 1 MiB
    float*    Hinit = (float*)   (ws + ((size_t)8 << 20) + (64 << 10));   // 1 MiB
    ushort_t* Harr  = (ushort_t*)(ws + ((size_t)10 << 20));               // 10..42 MiB: h~ then h

    // d_out (64 MiB fp32) doubles as bf16 scratch until GEMM2 overwrites it:
    ushort_t* Xb   = (ushort_t*)d_out;              // [0..32 MiB): x in bf16
    ushort_t* Zarr = Xb + (size_t)MM * DH;          // [32..64 MiB): post-sigmoid z

    dim3 blk(256);

    // x -> bf16
    cvt_f32_bf16<<<(MM * DIN / 4 + 255) / 256, blk, 0, stream>>>(x, Xb, MM * DIN);

    // Weight prep: WcatT rows n: [0,512)=Wzf, [512,1024)=Wzs, [1024,1536)=Whf, [1536,2048)=Whs
    transpose_cvt<<<dim3(16, 8),  blk, 0, stream>>>(Wzf, 512,  WcatT,                       DIN);
    transpose_cvt<<<dim3(16, 8),  blk, 0, stream>>>(Wzs, 512,  WcatT + (size_t)512  * DIN, DIN);
    transpose_cvt<<<dim3(16, 8),  blk, 0, stream>>>(Whf, 512,  WcatT + (size_t)1024 * DIN, DIN);
    transpose_cvt<<<dim3(16, 8),  blk, 0, stream>>>(Whs, 512,  WcatT + (size_t)1536 * DIN, DIN);
    transpose_cvt<<<dim3(16, 16), blk, 0, stream>>>(Wg,  1024, WgT,                         DIN);
    bias_concat<<<8, 256, 0, stream>>>(bzf, bzs, bhf, bhs, bcat);

    // GEMM1: Zarr = sigmoid(Xb@Wz+bz), Harr = Xb@Wh+bh   (M=16384, N=2048, K=1024)
    gemm_kernel<0><<<dim3(MM / 128, PN / 128), blk, 0, stream>>>(
        Xb, WcatT, DIN, /*lda=*/DIN, bcat, Zarr, Harr, nullptr, nullptr, nullptr);

    // Chunked scan (h written in place over Harr)
    scan_chunk_agg<<<dim3(DH / 256, NC, BB), blk, 0, stream>>>(Zarr, Harr, Agg, Bagg);
    scan_carry<<<16, 256, 0, stream>>>(Agg, Bagg, Hinit);
    scan_apply<<<dim3(DH / 256, NC, BB), blk, 0, stream>>>(Zarr, Harr, Hinit);

    // GEMM2: out = sigmoid(H @ Wg + bg) * H   (fp32 out, overwrites all of d_out)
    gemm_kernel<1><<<dim3(MM / 128, DH / 128), blk, 0, stream>>>(
        Harr, WgT, DIN, /*lda=*/DH, nullptr, nullptr, nullptr, bg, /*Hbf=*/Harr,
        (float*)d_out);
}

// Round 5
// 336.032 us; speedup vs baseline: 1.1044x; 1.1044x over previous
//
#include <hip/hip_runtime.h>

// Problem constants
#define BB 4
#define SS 4096
#define DIN 1024      // K for both GEMMs
#define DH 1024       // combined fast+slow channels
#define PN 2048       // GEMM1 logical output cols (z -> Zarr, h~ -> Harr)
#define MM (BB*SS)    // 16384 rows
#define NC 64         // scan chunks
#define CL 64         // chunk length (NC*CL == SS)

typedef unsigned short ushort_t;
typedef __attribute__((ext_vector_type(8))) short bf16x8;
typedef __attribute__((ext_vector_type(4))) float f32x4;
typedef __attribute__((ext_vector_type(4))) unsigned short u16x4;

__device__ inline float bf2f(ushort_t u) {
    union { float f; unsigned int i; } v; v.i = ((unsigned int)u) << 16; return v.f;
}
__device__ inline ushort_t f2bf(float f) {
    union { float f; unsigned int i; } v; v.f = f;
    unsigned int r = v.i + 0x7fffu + ((v.i >> 16) & 1u);  // round-to-nearest-even
    return (ushort_t)(r >> 16);
}
__device__ inline float sigmoidf_(float x) { return 1.0f / (1.0f + __expf(-x)); }

__device__ inline void load_lds16(const void* g, void* l) {
    __builtin_amdgcn_global_load_lds(
        (const __attribute__((address_space(1))) void*)g,
        (__attribute__((address_space(3))) void*)l, 16, 0, 0);
}

// ---------------------------------------------------------------------------
// Fallback (ws too small telemetry): write fp32 zeros to out.
__global__ void zero_out_kernel(float* out, int n) {
    int i = blockIdx.x * 256 + threadIdx.x;
    if (i < n) out[i] = 0.0f;
}

// ---------------------------------------------------------------------------
// Elementwise fp32 -> bf16 convert (n multiple of 4).
__global__ __launch_bounds__(256) void cvt_f32_bf16(
    const float* __restrict__ src, ushort_t* __restrict__ dst, int n)
{
    int i = (blockIdx.x * 256 + threadIdx.x) * 4;
    if (i >= n) return;
    float4 v = *(const float4*)(src + i);
    u16x4 o;
    o.x = f2bf(v.x); o.y = f2bf(v.y); o.z = f2bf(v.z); o.w = f2bf(v.w);
    *(u16x4*)(dst + i) = o;
}

// ---------------------------------------------------------------------------
// Transpose + convert: dst[n][k] = bf16(src[k][n]).  src: K x srcN fp32 rm.
// grid: (K/64, srcN/64), block 256.
__global__ __launch_bounds__(256) void transpose_cvt(
    const float* __restrict__ src, int srcN,
    ushort_t* __restrict__ dst, int K)
{
    __shared__ ushort_t tile[64][65];
    const int k0 = blockIdx.x * 64, n0 = blockIdx.y * 64;
    const int tx = threadIdx.x & 63, ty = threadIdx.x >> 6;  // ty in [0,4)
    #pragma unroll
    for (int i = ty; i < 64; i += 4)
        tile[i][tx] = f2bf(src[(size_t)(k0 + i) * srcN + n0 + tx]);
    __syncthreads();
    #pragma unroll
    for (int i = ty; i < 64; i += 4)
        dst[(size_t)(n0 + i) * K + k0 + tx] = tile[tx][i];
}

// ---------------------------------------------------------------------------
// Concatenate the four fp32 z/h biases into bcat[2048].
__global__ void bias_concat(const float* __restrict__ bzf, const float* __restrict__ bzs,
                            const float* __restrict__ bhf, const float* __restrict__ bhs,
                            float* __restrict__ bcat)
{
    int i = blockIdx.x * 256 + threadIdx.x;  // 0..2047
    float v = (i < 512) ? bzf[i] : (i < 1024) ? bzs[i - 512]
            : (i < 1536) ? bhf[i - 1024] : bhs[i - 1536];
    bcat[i] = v;
}

// ---------------------------------------------------------------------------
// GEMM: C(M x N) = A(M x K, bf16 rm, row stride lda) * Bt(N x K, bf16 rm)^T
// 128x128 tile, BK=64, 256 threads (4 waves 2x2, each 64x64 via 4x4 mfma 16x16x32).
//
// LDS layout is XOR-swizzled to kill the 16-way bank conflict of the naive
// row-major layout: row r's 16B chunk c lives at chunk position p = c ^ (r&7).
// The swizzle is applied on the *global source* side of global_load_lds (the
// LDS destination must stay base+lane*16 per the m104 contract); fragment
// reads invert it. Residual 2-way conflict (rows r, r+8) is free [m136].
//
// EPI=0 (N=2048): col<1024  -> Zarr[row*DH+col]      = bf16(sigmoid(acc+bias[col]))
//                 col>=1024 -> Harr[row*DH+col-1024] = bf16(acc+bias[col])
// EPI=1 (N=1024): Out[row*DH+col] = sigmoid(acc + bg[col]) * bf2f(Hbf[row*DH+col])  (fp32)
template <int EPI>
__global__ __launch_bounds__(256) void gemm_kernel(
    const ushort_t* __restrict__ A, const ushort_t* __restrict__ Bt,
    int K, int lda,
    const float* __restrict__ bias,
    ushort_t* __restrict__ Zarr, ushort_t* __restrict__ Harr,
    const float* __restrict__ bg, const ushort_t* __restrict__ Hbf,
    float* __restrict__ Out)
{
    __shared__ alignas(16) ushort_t As[128 * 64];
    __shared__ alignas(16) ushort_t Bs[128 * 64];

    const int tid  = threadIdx.x;
    const int lane = tid & 63;
    const int wave = tid >> 6;
    const int wm   = wave & 1;       // wave row (2x2 grid of waves)
    const int wn   = wave >> 1;      // wave col
    const int lrow = lane & 15;      // m (A) / n (B) / col (C)
    const int kgrp = lane >> 4;      // k-group: k = kgrp*8 + j

    const int mBase = blockIdx.x * 128;
    const int nBase = blockIdx.y * 128;

    f32x4 acc[4][4] = {};

    const ushort_t* Ablk = A  + (size_t)mBase * lda;
    const ushort_t* Bblk = Bt + (size_t)nBase * K;

    for (int k0 = 0; k0 < K; k0 += 64) {
        #pragma unroll
        for (int i = 0; i < 4; i++) {
            int idx = i * 256 + tid;                 // 0..1023 chunks of 16B
            int r   = idx >> 3;                      // row 0..127
            int cc  = ((idx & 7) ^ (r & 7)) * 8;     // swizzled source column
            load_lds16(Ablk + (size_t)r * lda + k0 + cc, &As[idx * 8]);
            load_lds16(Bblk + (size_t)r * K   + k0 + cc, &Bs[idx * 8]);
        }
        __syncthreads();                             // drains vmcnt for global_load_lds

        #pragma unroll
        for (int kk = 0; kk < 64; kk += 32) {
            const int c0 = (kk >> 3) + kgrp;         // chunk index pre-swizzle
            bf16x8 af[4], bfr[4];
            #pragma unroll
            for (int mt = 0; mt < 4; mt++) {
                int r = wm * 64 + mt * 16 + lrow;
                int p = c0 ^ (r & 7);
                af[mt] = *(const bf16x8*)&As[r * 64 + p * 8];
            }
            #pragma unroll
            for (int nt = 0; nt < 4; nt++) {
                int r = wn * 64 + nt * 16 + lrow;
                int p = c0 ^ (r & 7);
                bfr[nt] = *(const bf16x8*)&Bs[r * 64 + p * 8];
            }
            #pragma unroll
            for (int mt = 0; mt < 4; mt++)
                #pragma unroll
                for (int nt = 0; nt < 4; nt++)
                    acc[mt][nt] = __builtin_amdgcn_mfma_f32_16x16x32_bf16(
                        af[mt], bfr[nt], acc[mt][nt], 0, 0, 0);
        }
        __syncthreads();
    }

    // Epilogue. C/D layout: col = lane&15, row = (lane>>4)*4 + reg  [m89/m91]
    const int row0  = mBase + wm * 64;
    const int col0  = nBase + wn * 64;
    const int rquad = (lane >> 4) * 4;

    if (EPI == 0) {
        const bool isz = (nBase < DH);   // whole 128-col block is z-cols or h~-cols
        ushort_t* Dst  = isz ? Zarr : Harr;
        const int csub = isz ? 0 : DH;
        #pragma unroll
        for (int nt = 0; nt < 4; nt++) {
            int col  = col0 + nt * 16 + lrow;
            float bv = bias[col];
            int dcol = col - csub;
            #pragma unroll
            for (int mt = 0; mt < 4; mt++) {
                int row = row0 + mt * 16 + rquad;
                ushort_t* p = Dst + (size_t)row * DH + dcol;
                #pragma unroll
                for (int r = 0; r < 4; r++) {
                    float v = acc[mt][nt][r] + bv;
                    if (isz) v = sigmoidf_(v);
                    p[(size_t)r * DH] = f2bf(v);
                }
            }
        }
    } else {
        #pragma unroll
        for (int nt = 0; nt < 4; nt++) {
            int col  = col0 + nt * 16 + lrow;
            float bv = bg[col];
            #pragma unroll
            for (int mt = 0; mt < 4; mt++) {
                int row = row0 + mt * 16 + rquad;
                #pragma unroll
                for (int r = 0; r < 4; r++) {
                    float g = sigmoidf_(acc[mt][nt][r] + bv);
                    float h = bf2f(Hbf[(size_t)(row + r) * DH + col]);
                    Out[(size_t)(row + r) * DH + col] = g * h;
                }
            }
        }
    }
}

// ---------------------------------------------------------------------------
// Scan pass 1: per-chunk aggregates. h_t = a*h + b with a = 1-z, b = z*h_tilde.
__global__ __launch_bounds__(256) void scan_chunk_agg(
    const ushort_t* __restrict__ Zarr, const ushort_t* __restrict__ Harr,
    float* __restrict__ Agg, float* __restrict__ Bagg)
{
    const int c     = blockIdx.x * 256 + threadIdx.x;   // channel 0..1023
    const int chunk = blockIdx.y;
    const int b     = blockIdx.z;
    const size_t s0 = (size_t)(b * SS + chunk * CL);
    const ushort_t* Zp = Zarr + s0 * DH + c;
    const ushort_t* Hp = Harr + s0 * DH + c;
    float A = 1.0f, Bg = 0.0f;
    #pragma unroll 4
    for (int t = 0; t < CL; t++) {
        float z  = bf2f(Zp[(size_t)t * DH]);
        float ht = bf2f(Hp[(size_t)t * DH]);
        float a  = 1.0f - z;
        A  = A * a;
        Bg = a * Bg + z * ht;
    }
    const int idx = (b * NC + chunk) * DH + c;
    Agg[idx]  = A;
    Bagg[idx] = Bg;
}

// Scan pass 2: carry across chunks. 4096 threads, 64 sequential steps.
__global__ void scan_carry(const float* __restrict__ Agg, const float* __restrict__ Bagg,
                           float* __restrict__ Hinit)
{
    const int i = blockIdx.x * 256 + threadIdx.x;  // 0..4095
    const int b = i >> 10, c = i & 1023;
    float h = 0.0f;
    for (int j = 0; j < NC; j++) {
        const int idx = (b * NC + j) * DH + c;
        Hinit[idx] = h;
        h = Agg[idx] * h + Bagg[idx];
    }
}

// Scan pass 3: re-apply with chunk-initial h; write h (bf16) in place over Harr.
__global__ __launch_bounds__(256) void scan_apply(
    const ushort_t* __restrict__ Zarr, ushort_t* Harr, const float* __restrict__ Hinit)
{
    const int c     = blockIdx.x * 256 + threadIdx.x;
    const int chunk = blockIdx.y;
    const int b     = blockIdx.z;
    const size_t s0 = (size_t)(b * SS + chunk * CL);
    const ushort_t* Zp = Zarr + s0 * DH + c;
    ushort_t* Hp = Harr + s0 * DH + c;
    float h = Hinit[(b * NC + chunk) * DH + c];
    #pragma unroll 4
    for (int t = 0; t < CL; t++) {
        float z  = bf2f(Zp[(size_t)t * DH]);
        float ht = bf2f(Hp[(size_t)t * DH]);
        h = (1.0f - z) * h + z * ht;
        Hp[(size_t)t * DH] = f2bf(h);
    }
}

// ---------------------------------------------------------------------------
extern "C" void kernel_launch(void* const* d_in, const int* in_sizes, int n_in,
                              void* d_out, int out_size, void* d_ws, size_t ws_size,
                              hipStream_t stream)
{
    // All inputs fp32 per the reference; output fp32 (16M elements = 64 MiB).
    const float* x   = (const float*)d_in[0];
    const float* Wzf = (const float*)d_in[1];
    const float* bzf = (const float*)d_in[2];
    const float* Whf = (const float*)d_in[3];
    const float* bhf = (const float*)d_in[4];
    const float* Wzs = (const float*)d_in[5];
    const float* bzs = (const float*)d_in[6];
    const float* Whs = (const float*)d_in[7];
    const float* bhs = (const float*)d_in[8];
    const float* Wg  = (const float*)d_in[9];
    const float* bg  = (const float*)d_in[10];

    const size_t NEED = (size_t)42 << 20;   // 42 MiB
    if (ws_size < NEED) {
        zero_out_kernel<<<(MM * DH + 255) / 256, 256, 0, stream>>>((float*)d_out, MM * DH);
        return;
    }

    // Workspace layout (42 MiB):
    char* ws = (char*)d_ws;
    ushort_t* WcatT = (ushort_t*)(ws);                                    // 0..4 MiB: 2048x1024 bf16
    ushort_t* WgT   = (ushort_t*)(ws + ((size_t)4 << 20));                // 4..6 MiB: 1024x1024 bf16
    float*    bcat  = (float*)   (ws + ((size_t)6 << 20));                // 8 KiB
    float*    Agg   = (float*)   (ws + ((size_t)6 << 20) + (64 << 10));   // 1 MiB
    float*    Bagg  = (float*)   (ws + ((size_t)7 << 20) + (64 << 10));   // 1 MiB
    float*    Hinit = (float*)   (ws + ((size_t)8 << 20) + (64 << 10));   // 1 MiB
    ushort_t* Harr  = (ushort_t*)(ws + ((size_t)10 << 20));               // 10..42 MiB: h~ then h

    // d_out (64 MiB fp32) doubles as bf16 scratch until GEMM2 overwrites it:
    ushort_t* Xb   = (ushort_t*)d_out;              // [0..32 MiB): x in bf16
    ushort_t* Zarr = Xb + (size_t)MM * DH;          // [32..64 MiB): post-sigmoid z

    dim3 blk(256);

    // x -> bf16
    cvt_f32_bf16<<<(MM * DIN / 4 + 255) / 256, blk, 0, stream>>>(x, Xb, MM * DIN);

    // Weight prep: WcatT rows n: [0,512)=Wzf, [512,1024)=Wzs, [1024,1536)=Whf, [1536,2048)=Whs
    transpose_cvt<<<dim3(16, 8),  blk, 0, stream>>>(Wzf, 512,  WcatT,                       DIN);
    transpose_cvt<<<dim3(16, 8),  blk, 0, stream>>>(Wzs, 512,  WcatT + (size_t)512  * DIN, DIN);
    transpose_cvt<<<dim3(16, 8),  blk, 0, stream>>>(Whf, 512,  WcatT + (size_t)1024 * DIN, DIN);
    transpose_cvt<<<dim3(16, 8),  blk, 0, stream>>>(Whs, 512,  WcatT + (size_t)1536 * DIN, DIN);
    transpose_cvt<<<dim3(16, 16), blk, 0, stream>>>(Wg,  1024, WgT,                         DIN);
    bias_concat<<<8, 256, 0, stream>>>(bzf, bzs, bhf, bhs, bcat);

    // GEMM1: Zarr = sigmoid(Xb@Wz+bz), Harr = Xb@Wh+bh   (M=16384, N=2048, K=1024)
    gemm_kernel<0><<<dim3(MM / 128, PN / 128), blk, 0, stream>>>(
        Xb, WcatT, DIN, /*lda=*/DIN, bcat, Zarr, Harr, nullptr, nullptr, nullptr);

    // Chunked scan (h written in place over Harr)
    scan_chunk_agg<<<dim3(DH / 256, NC, BB), blk, 0, stream>>>(Zarr, Harr, Agg, Bagg);
    scan_carry<<<16, 256, 0, stream>>>(Agg, Bagg, Hinit);
    scan_apply<<<dim3(DH / 256, NC, BB), blk, 0, stream>>>(Zarr, Harr, Hinit);

    // GEMM2: out = sigmoid(H @ Wg + bg) * H   (fp32 out, overwrites all of d_out)
    gemm_kernel<1><<<dim3(MM / 128, DH / 128), blk, 0, stream>>>(
        Harr, WgT, DIN, /*lda=*/DH, nullptr, nullptr, nullptr, bg, /*Hbf=*/Harr,
        (float*)d_out);
}